// Round 2
// baseline (1281.404 us; speedup 1.0000x reference)
//
#include <hip/hip_runtime.h>

#define NN 100000
#define NE 1600000

// ---------------- structure precompute ----------------

__global__ void k_zero_deg(int* __restrict__ deg, int n) {
    int i = blockIdx.x * blockDim.x + threadIdx.x;
    if (i < n) deg[i] = 0;
}

// count in-degree (edge_index arrives as int32: harness converts integer inputs)
__global__ void k_count(const int* __restrict__ ei, int* __restrict__ deg, int nE) {
    int e = blockIdx.x * blockDim.x + threadIdx.x;
    if (e >= nE) return;
    int d = ei[nE + e];
    atomicAdd(&deg[d], 1);
}

__global__ void k_dinv(const int* __restrict__ deg, float* __restrict__ dinv, int n) {
    int i = blockIdx.x * blockDim.x + threadIdx.x;
    if (i < n) dinv[i] = rsqrtf((float)(deg[i] + 1));  // +1 = self loop
}

__global__ void k_norm(const int* __restrict__ ei, const float* __restrict__ dinv,
                       float* __restrict__ norm, int nE) {
    int e = blockIdx.x * blockDim.x + threadIdx.x;
    if (e >= nE) return;
    norm[e] = dinv[ei[e]] * dinv[ei[nE + e]];
}

// ---------------- per-layer kernels ----------------

// One thread per node: xw[node] = (relu?)h[node] @ W ; and initialize
// hout[node] = b + xw[node]*dinv^2 (+ x_orig if LAST).
template <int DIN, int DOUT, bool RELU_IN, bool LAST>
__global__ __launch_bounds__(256) void k_gemm(
    const float* __restrict__ hin, const float* __restrict__ Wg,
    const float* __restrict__ bg, const float* __restrict__ dinv,
    const float* __restrict__ xorig,
    float* __restrict__ xw, float* __restrict__ hout, int n) {
    __shared__ float sW[DIN * DOUT];
    __shared__ float sb[DOUT];
    for (int i = threadIdx.x; i < DIN * DOUT; i += blockDim.x) sW[i] = Wg[i];
    if (threadIdx.x < DOUT) sb[threadIdx.x] = bg[threadIdx.x];
    __syncthreads();

    int node = blockIdx.x * blockDim.x + threadIdx.x;
    if (node >= n) return;

    float h[DIN];
#pragma unroll
    for (int k = 0; k < DIN; ++k) {
        float v = hin[node * DIN + k];
        if (RELU_IN) v = fmaxf(v, 0.0f);
        h[k] = v;
    }
    float di = dinv[node];
    float selfw = di * di;

#pragma unroll
    for (int f = 0; f < DOUT; ++f) {
        float acc = 0.0f;
#pragma unroll
        for (int k = 0; k < DIN; ++k) acc = fmaf(h[k], sW[k * DOUT + f], acc);
        xw[node * DOUT + f] = acc;
        float o = sb[f] + acc * selfw;
        if (LAST) o += xorig[node * 2 + f];
        hout[node * DOUT + f] = o;
    }
}

// One thread per (edge, feature): hout[dst] += xw[src] * norm[e]
template <int DOUT>
__global__ __launch_bounds__(256) void k_scatter(
    const int* __restrict__ ei, const float* __restrict__ norm,
    const float* __restrict__ xw, float* __restrict__ hout, int nE) {
    long long t = (long long)blockIdx.x * blockDim.x + threadIdx.x;
    long long e = t / DOUT;
    int f = (int)(t % DOUT);
    if (e >= nE) return;
    int s = ei[e];
    int d = ei[nE + e];
    float v = xw[s * DOUT + f] * norm[e];
    atomicAdd(&hout[d * DOUT + f], v);
}

// ---------------- launch ----------------

extern "C" void kernel_launch(void* const* d_in, const int* in_sizes, int n_in,
                              void* d_out, int out_size, void* d_ws, size_t ws_size,
                              hipStream_t stream) {
    const float* x = (const float*)d_in[0];
    const int* ei = (const int*)d_in[1];  // int32: harness converts integer inputs
    const float* W[8];
    const float* B[8];
    for (int i = 0; i < 8; ++i) {
        W[i] = (const float*)d_in[2 + 2 * i];
        B[i] = (const float*)d_in[3 + 2 * i];
    }
    float* out = (float*)d_out;

    char* ws = (char*)d_ws;
    int*   deg  = (int*)  (ws + 0);          //   0.4 MB
    float* dinv = (float*)(ws + 400000);     //   0.4 MB
    float* norm = (float*)(ws + 800000);     //   6.4 MB
    float* hA   = (float*)(ws + 7200000);    //  12.8 MB
    float* hB   = (float*)(ws + 20000000);   //  12.8 MB
    float* xw   = (float*)(ws + 32800000);   //  12.8 MB  (total 45.6 MB)

    dim3 blk(256);
    int gN = (NN + 255) / 256;
    int gE = (NE + 255) / 256;

    k_zero_deg<<<gN, blk, 0, stream>>>(deg, NN);
    k_count<<<gE, blk, 0, stream>>>(ei, deg, NE);
    k_dinv<<<gN, blk, 0, stream>>>(deg, dinv, NN);
    k_norm<<<gE, blk, 0, stream>>>(ei, dinv, norm, NE);

    auto gScat = [](int dout) { return (int)(((long long)NE * dout + 255) / 256); };

    // L1: x(2) -> hA(16)
    k_gemm<2, 16, false, false><<<gN, blk, 0, stream>>>(x, W[0], B[0], dinv, x, xw, hA, NN);
    k_scatter<16><<<gScat(16), blk, 0, stream>>>(ei, norm, xw, hA, NE);
    // L2: hA(16) -> hB(32)
    k_gemm<16, 32, true, false><<<gN, blk, 0, stream>>>(hA, W[1], B[1], dinv, x, xw, hB, NN);
    k_scatter<32><<<gScat(32), blk, 0, stream>>>(ei, norm, xw, hB, NE);
    // L3: hB(32) -> hA(32)
    k_gemm<32, 32, true, false><<<gN, blk, 0, stream>>>(hB, W[2], B[2], dinv, x, xw, hA, NN);
    k_scatter<32><<<gScat(32), blk, 0, stream>>>(ei, norm, xw, hA, NE);
    // L4: hA(32) -> hB(32)
    k_gemm<32, 32, true, false><<<gN, blk, 0, stream>>>(hA, W[3], B[3], dinv, x, xw, hB, NN);
    k_scatter<32><<<gScat(32), blk, 0, stream>>>(ei, norm, xw, hB, NE);
    // L5: hB(32) -> hA(32)
    k_gemm<32, 32, true, false><<<gN, blk, 0, stream>>>(hB, W[4], B[4], dinv, x, xw, hA, NN);
    k_scatter<32><<<gScat(32), blk, 0, stream>>>(ei, norm, xw, hA, NE);
    // L6: hA(32) -> hB(32)
    k_gemm<32, 32, true, false><<<gN, blk, 0, stream>>>(hA, W[5], B[5], dinv, x, xw, hB, NN);
    k_scatter<32><<<gScat(32), blk, 0, stream>>>(ei, norm, xw, hB, NE);
    // L7: hB(32) -> hA(16)
    k_gemm<32, 16, true, false><<<gN, blk, 0, stream>>>(hB, W[6], B[6], dinv, x, xw, hA, NN);
    k_scatter<16><<<gScat(16), blk, 0, stream>>>(ei, norm, xw, hA, NE);
    // L8: hA(16) -> out(2), fused +x_orig
    k_gemm<16, 2, true, true><<<gN, blk, 0, stream>>>(hA, W[7], B[7], dinv, x, xw, out, NN);
    k_scatter<2><<<gScat(2), blk, 0, stream>>>(ei, norm, xw, out, NE);
}

// Round 3
// 1094.891 us; speedup vs baseline: 1.1703x; 1.1703x over previous
//
#include <hip/hip_runtime.h>

#define NN 100000
#define NE 1600000
#define SCAN_T 1024

// ---------------- structure precompute ----------------

__global__ void k_zero_deg(int* __restrict__ deg, int n) {
    int i = blockIdx.x * blockDim.x + threadIdx.x;
    if (i < n) deg[i] = 0;
}

__global__ void k_count(const int* __restrict__ ei, int* __restrict__ deg, int nE) {
    int e = blockIdx.x * blockDim.x + threadIdx.x;
    if (e >= nE) return;
    atomicAdd(&deg[ei[nE + e]], 1);
}

__global__ void k_dinv(const int* __restrict__ deg, float* __restrict__ dinv, int n) {
    int i = blockIdx.x * blockDim.x + threadIdx.x;
    if (i < n) dinv[i] = rsqrtf((float)(deg[i] + 1));  // +1 = self loop
}

// single-block exclusive scan: deg -> rowptr[n+1], cursor copy
__global__ __launch_bounds__(SCAN_T) void k_scan(
    const int* __restrict__ deg, int* __restrict__ rowptr,
    int* __restrict__ cursor, int n) {
    __shared__ int part[SCAN_T];
    int tid = threadIdx.x;
    int per = (n + SCAN_T - 1) / SCAN_T;
    int lo = tid * per;
    int hi = lo + per; if (hi > n) hi = n;
    int sum = 0;
    for (int i = lo; i < hi; ++i) sum += deg[i];
    part[tid] = sum;
    __syncthreads();
    for (int off = 1; off < SCAN_T; off <<= 1) {
        int v = part[tid];
        int add = (tid >= off) ? part[tid - off] : 0;
        __syncthreads();
        part[tid] = v + add;
        __syncthreads();
    }
    int base = (tid > 0) ? part[tid - 1] : 0;
    for (int i = lo; i < hi; ++i) {
        rowptr[i] = base;
        cursor[i] = base;
        base += deg[i];
    }
    if (tid == SCAN_T - 1) rowptr[n] = part[SCAN_T - 1];
}

// group edges by dst: csr_src[pos]=src, csr_w[pos]=norm
__global__ void k_fill(const int* __restrict__ ei, const float* __restrict__ dinv,
                       int* __restrict__ cursor, int* __restrict__ csr_src,
                       float* __restrict__ csr_w, int nE) {
    int e = blockIdx.x * blockDim.x + threadIdx.x;
    if (e >= nE) return;
    int s = ei[e];
    int d = ei[nE + e];
    int pos = atomicAdd(&cursor[d], 1);
    csr_src[pos] = s;
    csr_w[pos] = dinv[s] * dinv[d];
}

// ---------------- per-layer kernels ----------------

// xw[node] = h[node] @ W  (h is already post-activation)
template <int DIN, int DOUT>
__global__ __launch_bounds__(256) void k_xw(
    const float* __restrict__ hin, const float* __restrict__ Wg,
    float* __restrict__ xw, int n) {
    __shared__ float sW[DIN * DOUT];
    for (int i = threadIdx.x; i < DIN * DOUT; i += blockDim.x) sW[i] = Wg[i];
    __syncthreads();

    int node = blockIdx.x * blockDim.x + threadIdx.x;
    if (node >= n) return;

    float h[DIN];
#pragma unroll
    for (int k = 0; k < DIN; ++k) h[k] = hin[node * DIN + k];

#pragma unroll
    for (int f = 0; f < DOUT; ++f) {
        float acc = 0.0f;
#pragma unroll
        for (int k = 0; k < DIN; ++k) acc = fmaf(h[k], sW[k * DOUT + f], acc);
        xw[node * DOUT + f] = acc;
    }
}

// gather: hout[v][f] = act(b[f] + xw[v][f]*dinv[v]^2 + sum_j xw[csr_src[j]][f]*csr_w[j])
// group of DOUT lanes per node; lane = feature.
template <int DOUT, bool RELU_OUT, bool LAST>
__global__ __launch_bounds__(256) void k_gather(
    const int* __restrict__ rowptr, const int* __restrict__ csr_src,
    const float* __restrict__ csr_w, const float* __restrict__ xw,
    const float* __restrict__ bg, const float* __restrict__ dinv,
    const float* __restrict__ xorig, float* __restrict__ hout, int n) {
    const int gpb = 256 / DOUT;
    int v = blockIdx.x * gpb + threadIdx.x / DOUT;
    int f = threadIdx.x % DOUT;
    if (v >= n) return;
    int lo = rowptr[v];
    int hi = rowptr[v + 1];
    float acc = 0.0f;
    for (int j = lo; j < hi; ++j) {
        int s = csr_src[j];      // uniform within group -> broadcast
        float w = csr_w[j];
        acc = fmaf(xw[s * DOUT + f], w, acc);
    }
    float di = dinv[v];
    float o = bg[f] + acc + xw[v * DOUT + f] * (di * di);
    if (RELU_OUT) o = fmaxf(o, 0.0f);
    if (LAST) o += xorig[v * 2 + f];
    hout[v * DOUT + f] = o;
}

// ---------------- launch ----------------

extern "C" void kernel_launch(void* const* d_in, const int* in_sizes, int n_in,
                              void* d_out, int out_size, void* d_ws, size_t ws_size,
                              hipStream_t stream) {
    const float* x = (const float*)d_in[0];
    const int* ei = (const int*)d_in[1];  // int32 (harness converts integer inputs)
    const float* W[8];
    const float* B[8];
    for (int i = 0; i < 8; ++i) {
        W[i] = (const float*)d_in[2 + 2 * i];
        B[i] = (const float*)d_in[3 + 2 * i];
    }
    float* out = (float*)d_out;

    char* ws = (char*)d_ws;
    int*   deg     = (int*)  (ws + 0);          //  0.4 MB
    float* dinv    = (float*)(ws + 400000);     //  0.4 MB
    int*   rowptr  = (int*)  (ws + 800000);     //  0.41 MB (n+1)
    int*   cursor  = (int*)  (ws + 1210000);    //  0.4 MB
    int*   csr_src = (int*)  (ws + 1610000);    //  6.4 MB
    float* csr_w   = (float*)(ws + 8010000);    //  6.4 MB
    float* xw      = (float*)(ws + 14410000);   // 12.8 MB
    float* act     = (float*)(ws + 27210000);   // 12.8 MB  (total 40 MB)

    dim3 blk(256);
    int gN = (NN + 255) / 256;
    int gE = (NE + 255) / 256;

    k_zero_deg<<<gN, blk, 0, stream>>>(deg, NN);
    k_count<<<gE, blk, 0, stream>>>(ei, deg, NE);
    k_dinv<<<gN, blk, 0, stream>>>(deg, dinv, NN);
    k_scan<<<1, SCAN_T, 0, stream>>>(deg, rowptr, cursor, NN);
    k_fill<<<gE, blk, 0, stream>>>(ei, dinv, cursor, csr_src, csr_w, NE);

    auto gG = [](int dout) { return (NN + (256 / dout) - 1) / (256 / dout); };

    // L1: x(2) -> act(16)
    k_xw<2, 16><<<gN, blk, 0, stream>>>(x, W[0], xw, NN);
    k_gather<16, true, false><<<gG(16), blk, 0, stream>>>(rowptr, csr_src, csr_w, xw, B[0], dinv, x, act, NN);
    // L2: act(16) -> act(32)
    k_xw<16, 32><<<gN, blk, 0, stream>>>(act, W[1], xw, NN);
    k_gather<32, true, false><<<gG(32), blk, 0, stream>>>(rowptr, csr_src, csr_w, xw, B[1], dinv, x, act, NN);
    // L3..L6: act(32) -> act(32)
    k_xw<32, 32><<<gN, blk, 0, stream>>>(act, W[2], xw, NN);
    k_gather<32, true, false><<<gG(32), blk, 0, stream>>>(rowptr, csr_src, csr_w, xw, B[2], dinv, x, act, NN);
    k_xw<32, 32><<<gN, blk, 0, stream>>>(act, W[3], xw, NN);
    k_gather<32, true, false><<<gG(32), blk, 0, stream>>>(rowptr, csr_src, csr_w, xw, B[3], dinv, x, act, NN);
    k_xw<32, 32><<<gN, blk, 0, stream>>>(act, W[4], xw, NN);
    k_gather<32, true, false><<<gG(32), blk, 0, stream>>>(rowptr, csr_src, csr_w, xw, B[4], dinv, x, act, NN);
    k_xw<32, 32><<<gN, blk, 0, stream>>>(act, W[5], xw, NN);
    k_gather<32, true, false><<<gG(32), blk, 0, stream>>>(rowptr, csr_src, csr_w, xw, B[5], dinv, x, act, NN);
    // L7: act(32) -> act(16)
    k_xw<32, 16><<<gN, blk, 0, stream>>>(act, W[6], xw, NN);
    k_gather<16, true, false><<<gG(16), blk, 0, stream>>>(rowptr, csr_src, csr_w, xw, B[6], dinv, x, act, NN);
    // L8: act(16) -> out(2), fused +x_orig, no relu
    k_xw<16, 2><<<gN, blk, 0, stream>>>(act, W[7], xw, NN);
    k_gather<2, false, true><<<gG(2), blk, 0, stream>>>(rowptr, csr_src, csr_w, xw, B[7], dinv, x, out, NN);
}

// Round 4
// 876.883 us; speedup vs baseline: 1.4613x; 1.2486x over previous
//
#include <hip/hip_runtime.h>

#define NN 100000
#define NE 1600000
#define SCAN_BLK 1024
#define NBLK ((NN + SCAN_BLK - 1) / SCAN_BLK)   // 98

// ---------------- structure precompute ----------------

__global__ void k_zero_deg(int* __restrict__ deg, int n) {
    int i = blockIdx.x * blockDim.x + threadIdx.x;
    if (i < n) deg[i] = 0;
}

__global__ void k_count(const int* __restrict__ ei, int* __restrict__ deg, int nE) {
    int e = blockIdx.x * blockDim.x + threadIdx.x;
    if (e >= nE) return;
    atomicAdd(&deg[ei[nE + e]], 1);
}

// stage 1: per-block inclusive scan; writes exclusive-within-block + block sum
__global__ __launch_bounds__(SCAN_BLK) void k_scan1(
    const int* __restrict__ deg, int* __restrict__ exc, int* __restrict__ bsum, int n) {
    __shared__ int sh[SCAN_BLK];
    int tid = threadIdx.x;
    int i = blockIdx.x * SCAN_BLK + tid;
    int v = (i < n) ? deg[i] : 0;
    sh[tid] = v;
    __syncthreads();
    for (int off = 1; off < SCAN_BLK; off <<= 1) {
        int add = (tid >= off) ? sh[tid - off] : 0;
        __syncthreads();
        sh[tid] += add;
        __syncthreads();
    }
    if (i < n) exc[i] = sh[tid] - v;
    if (tid == SCAN_BLK - 1) bsum[blockIdx.x] = sh[tid];
}

// stage 2: exclusive scan of NBLK block sums (single small block)
__global__ __launch_bounds__(128) void k_scan2(int* __restrict__ bsum, int nb) {
    __shared__ int sh[128];
    int tid = threadIdx.x;
    int v = (tid < nb) ? bsum[tid] : 0;
    sh[tid] = v;
    __syncthreads();
    for (int off = 1; off < 128; off <<= 1) {
        int add = (tid >= off) ? sh[tid - off] : 0;
        __syncthreads();
        sh[tid] += add;
        __syncthreads();
    }
    if (tid < nb) bsum[tid] = sh[tid] - v;  // exclusive
}

// stage 3: rowptr = exc + block offset; cursor copy; fused dinv
__global__ __launch_bounds__(SCAN_BLK) void k_scan3(
    const int* __restrict__ exc, const int* __restrict__ bsum,
    const int* __restrict__ deg, int* __restrict__ rowptr,
    int* __restrict__ cursor, float* __restrict__ dinv, int n) {
    int i = blockIdx.x * SCAN_BLK + threadIdx.x;
    if (i >= n) return;
    int r = exc[i] + bsum[blockIdx.x];
    rowptr[i] = r;
    cursor[i] = r;
    dinv[i] = rsqrtf((float)(deg[i] + 1));  // +1 = self loop
    if (i == 0) rowptr[n] = NE;             // total degree is statically known
}

// group edges by dst: csr_src[pos]=src, csr_w[pos]=norm
__global__ void k_fill(const int* __restrict__ ei, const float* __restrict__ dinv,
                       int* __restrict__ cursor, int* __restrict__ csr_src,
                       float* __restrict__ csr_w, int nE) {
    int e = blockIdx.x * blockDim.x + threadIdx.x;
    if (e >= nE) return;
    int s = ei[e];
    int d = ei[nE + e];
    int pos = atomicAdd(&cursor[d], 1);
    csr_src[pos] = s;
    csr_w[pos] = dinv[s] * dinv[d];
}

// ---------------- per-layer kernels ----------------

// xw[node] = h[node] @ W  (h is already post-activation)
template <int DIN, int DOUT>
__global__ __launch_bounds__(256) void k_xw(
    const float* __restrict__ hin, const float* __restrict__ Wg,
    float* __restrict__ xw, int n) {
    __shared__ float sW[DIN * DOUT];
    for (int i = threadIdx.x; i < DIN * DOUT; i += blockDim.x) sW[i] = Wg[i];
    __syncthreads();

    int node = blockIdx.x * blockDim.x + threadIdx.x;
    if (node >= n) return;

    float h[DIN];
#pragma unroll
    for (int k = 0; k < DIN; ++k) h[k] = hin[node * DIN + k];

#pragma unroll
    for (int f = 0; f < DOUT; ++f) {
        float acc = 0.0f;
#pragma unroll
        for (int k = 0; k < DIN; ++k) acc = fmaf(h[k], sW[k * DOUT + f], acc);
        xw[node * DOUT + f] = acc;
    }
}

// gather: hout[v][f] = act(b[f] + xw[v][f]*dinv[v]^2 + sum_j xw[csr_src[j]][f]*csr_w[j])
// group of DOUT lanes per node; lane = feature.
template <int DOUT, bool RELU_OUT, bool LAST>
__global__ __launch_bounds__(256) void k_gather(
    const int* __restrict__ rowptr, const int* __restrict__ csr_src,
    const float* __restrict__ csr_w, const float* __restrict__ xw,
    const float* __restrict__ bg, const float* __restrict__ dinv,
    const float* __restrict__ xorig, float* __restrict__ hout, int n) {
    const int gpb = 256 / DOUT;
    int v = blockIdx.x * gpb + threadIdx.x / DOUT;
    int f = threadIdx.x % DOUT;
    if (v >= n) return;
    int lo = rowptr[v];
    int hi = rowptr[v + 1];
    float acc = 0.0f;
    for (int j = lo; j < hi; ++j) {
        int s = csr_src[j];      // uniform within group -> broadcast
        float w = csr_w[j];
        acc = fmaf(xw[s * DOUT + f], w, acc);
    }
    float di = dinv[v];
    float o = bg[f] + acc + xw[v * DOUT + f] * (di * di);
    if (RELU_OUT) o = fmaxf(o, 0.0f);
    if (LAST) o += xorig[v * 2 + f];
    hout[v * DOUT + f] = o;
}

// ---------------- launch ----------------

extern "C" void kernel_launch(void* const* d_in, const int* in_sizes, int n_in,
                              void* d_out, int out_size, void* d_ws, size_t ws_size,
                              hipStream_t stream) {
    const float* x = (const float*)d_in[0];
    const int* ei = (const int*)d_in[1];  // int32 (harness converts integer inputs)
    const float* W[8];
    const float* B[8];
    for (int i = 0; i < 8; ++i) {
        W[i] = (const float*)d_in[2 + 2 * i];
        B[i] = (const float*)d_in[3 + 2 * i];
    }
    float* out = (float*)d_out;

    char* ws = (char*)d_ws;
    int*   deg     = (int*)  (ws + 0);          //  0.4 MB
    float* dinv    = (float*)(ws + 400000);     //  0.4 MB
    int*   rowptr  = (int*)  (ws + 800000);     //  0.41 MB (n+1)
    int*   cursor  = (int*)  (ws + 1210000);    //  0.4 MB
    int*   exc     = (int*)  (ws + 1610000);    //  0.4 MB
    int*   bsum    = (int*)  (ws + 2010000);    //  small
    int*   csr_src = (int*)  (ws + 2020000);    //  6.4 MB
    float* csr_w   = (float*)(ws + 8420000);    //  6.4 MB
    float* xw      = (float*)(ws + 14820000);   // 12.8 MB
    float* act     = (float*)(ws + 27620000);   // 12.8 MB  (total ~40.4 MB)

    dim3 blk(256);
    int gN = (NN + 255) / 256;
    int gE = (NE + 255) / 256;

    k_zero_deg<<<gN, blk, 0, stream>>>(deg, NN);
    k_count<<<gE, blk, 0, stream>>>(ei, deg, NE);
    k_scan1<<<NBLK, SCAN_BLK, 0, stream>>>(deg, exc, bsum, NN);
    k_scan2<<<1, 128, 0, stream>>>(bsum, NBLK);
    k_scan3<<<NBLK, SCAN_BLK, 0, stream>>>(exc, bsum, deg, rowptr, cursor, dinv, NN);
    k_fill<<<gE, blk, 0, stream>>>(ei, dinv, cursor, csr_src, csr_w, NE);

    auto gG = [](int dout) { return (NN + (256 / dout) - 1) / (256 / dout); };

    // L1: x(2) -> act(16)
    k_xw<2, 16><<<gN, blk, 0, stream>>>(x, W[0], xw, NN);
    k_gather<16, true, false><<<gG(16), blk, 0, stream>>>(rowptr, csr_src, csr_w, xw, B[0], dinv, x, act, NN);
    // L2: act(16) -> act(32)
    k_xw<16, 32><<<gN, blk, 0, stream>>>(act, W[1], xw, NN);
    k_gather<32, true, false><<<gG(32), blk, 0, stream>>>(rowptr, csr_src, csr_w, xw, B[1], dinv, x, act, NN);
    // L3..L6: act(32) -> act(32)
    k_xw<32, 32><<<gN, blk, 0, stream>>>(act, W[2], xw, NN);
    k_gather<32, true, false><<<gG(32), blk, 0, stream>>>(rowptr, csr_src, csr_w, xw, B[2], dinv, x, act, NN);
    k_xw<32, 32><<<gN, blk, 0, stream>>>(act, W[3], xw, NN);
    k_gather<32, true, false><<<gG(32), blk, 0, stream>>>(rowptr, csr_src, csr_w, xw, B[3], dinv, x, act, NN);
    k_xw<32, 32><<<gN, blk, 0, stream>>>(act, W[4], xw, NN);
    k_gather<32, true, false><<<gG(32), blk, 0, stream>>>(rowptr, csr_src, csr_w, xw, B[4], dinv, x, act, NN);
    k_xw<32, 32><<<gN, blk, 0, stream>>>(act, W[5], xw, NN);
    k_gather<32, true, false><<<gG(32), blk, 0, stream>>>(rowptr, csr_src, csr_w, xw, B[5], dinv, x, act, NN);
    // L7: act(32) -> act(16)
    k_xw<32, 16><<<gN, blk, 0, stream>>>(act, W[6], xw, NN);
    k_gather<16, true, false><<<gG(16), blk, 0, stream>>>(rowptr, csr_src, csr_w, xw, B[6], dinv, x, act, NN);
    // L8: act(16) -> out(2), fused +x_orig, no relu
    k_xw<16, 2><<<gN, blk, 0, stream>>>(act, W[7], xw, NN);
    k_gather<2, false, true><<<gG(2), blk, 0, stream>>>(rowptr, csr_src, csr_w, xw, B[7], dinv, x, out, NN);
}

// Round 5
// 670.309 us; speedup vs baseline: 1.9117x; 1.3082x over previous
//
#include <hip/hip_runtime.h>

#define NN 100000
#define NE 1600000
#define SCAN_BLK 1024
#define NBLK ((NN + SCAN_BLK - 1) / SCAN_BLK)   // 98

// ---------------- structure precompute ----------------

__global__ void k_zero_deg(int* __restrict__ deg, int n) {
    int i = blockIdx.x * blockDim.x + threadIdx.x;
    if (i < n) deg[i] = 0;
}

__global__ void k_count(const int* __restrict__ ei, int* __restrict__ deg, int nE) {
    int e = blockIdx.x * blockDim.x + threadIdx.x;
    if (e >= nE) return;
    atomicAdd(&deg[ei[nE + e]], 1);
}

__global__ __launch_bounds__(SCAN_BLK) void k_scan1(
    const int* __restrict__ deg, int* __restrict__ exc, int* __restrict__ bsum, int n) {
    __shared__ int sh[SCAN_BLK];
    int tid = threadIdx.x;
    int i = blockIdx.x * SCAN_BLK + tid;
    int v = (i < n) ? deg[i] : 0;
    sh[tid] = v;
    __syncthreads();
    for (int off = 1; off < SCAN_BLK; off <<= 1) {
        int add = (tid >= off) ? sh[tid - off] : 0;
        __syncthreads();
        sh[tid] += add;
        __syncthreads();
    }
    if (i < n) exc[i] = sh[tid] - v;
    if (tid == SCAN_BLK - 1) bsum[blockIdx.x] = sh[tid];
}

__global__ __launch_bounds__(128) void k_scan2(int* __restrict__ bsum, int nb) {
    __shared__ int sh[128];
    int tid = threadIdx.x;
    int v = (tid < nb) ? bsum[tid] : 0;
    sh[tid] = v;
    __syncthreads();
    for (int off = 1; off < 128; off <<= 1) {
        int add = (tid >= off) ? sh[tid - off] : 0;
        __syncthreads();
        sh[tid] += add;
        __syncthreads();
    }
    if (tid < nb) bsum[tid] = sh[tid] - v;  // exclusive
}

__global__ __launch_bounds__(SCAN_BLK) void k_scan3(
    const int* __restrict__ exc, const int* __restrict__ bsum,
    const int* __restrict__ deg, int* __restrict__ rowptr,
    int* __restrict__ cursor, float* __restrict__ dinv, int n) {
    int i = blockIdx.x * SCAN_BLK + threadIdx.x;
    if (i >= n) return;
    int r = exc[i] + bsum[blockIdx.x];
    rowptr[i] = r;
    cursor[i] = r;
    dinv[i] = rsqrtf((float)(deg[i] + 1));  // +1 = self loop
    if (i == 0) rowptr[n] = NE;
}

// group edges by dst (only src index needed; norm folded into hd arrays)
__global__ void k_fill(const int* __restrict__ ei, int* __restrict__ cursor,
                       int* __restrict__ csr_src, int nE) {
    int e = blockIdx.x * blockDim.x + threadIdx.x;
    if (e >= nE) return;
    int s = ei[e];
    int d = ei[nE + e];
    int pos = atomicAdd(&cursor[d], 1);
    csr_src[pos] = s;
}

// hd0 = x * dinv  (per element)
__global__ void k_prep(const float* __restrict__ x, const float* __restrict__ dinv,
                       float* __restrict__ hd0, int n2) {
    int t = blockIdx.x * blockDim.x + threadIdx.x;
    if (t >= n2) return;
    hd0[t] = x[t] * dinv[t >> 1];
}

// ---------------- layer kernels ----------------
// Layer math: agg[v] = dinv[v] * (sum_{j in row(v)} hd_in[src_j] + hd_in[v])
//             o      = agg @ W + b ;  hd_out = relu(o)*dinv  (or o + xorig if LAST)

// L1 special: DIN=2. Group of 16 lanes splits the edge list; butterfly reduce.
__global__ __launch_bounds__(256) void k_layer1(
    const int* __restrict__ rowptr, const int* __restrict__ csr_src,
    const float2* __restrict__ hd0, const float* __restrict__ Wg,
    const float* __restrict__ bg, const float* __restrict__ dinv,
    float* __restrict__ hd1, int n) {
    __shared__ float sW[32];
    if (threadIdx.x < 32) sW[threadIdx.x] = Wg[threadIdx.x];
    __syncthreads();
    int v = blockIdx.x * 16 + threadIdx.x / 16;
    int l = threadIdx.x & 15;
    if (v >= n) return;
    int lo = rowptr[v], hi = rowptr[v + 1];
    float a0 = 0.f, a1 = 0.f;
    for (int j = lo + l; j < hi; j += 16) {
        float2 h = hd0[csr_src[j]];
        a0 += h.x; a1 += h.y;
    }
#pragma unroll
    for (int off = 8; off >= 1; off >>= 1) {
        a0 += __shfl_xor(a0, off, 16);
        a1 += __shfl_xor(a1, off, 16);
    }
    float dv = dinv[v];
    float2 hs = hd0[v];
    a0 = (a0 + hs.x) * dv;
    a1 = (a1 + hs.y) * dv;
    float o = bg[l] + a0 * sW[l] + a1 * sW[16 + l];   // W is (2,16) row-major
    hd1[v * 16 + l] = fmaxf(o, 0.f) * dv;
}

// Generic layer. Lanes-per-group = DIN * (TWOWAY?2:1); feature lane f, edge-way.
template <int DIN, int DOUT, bool RELU, bool LAST, bool TWOWAY>
__global__ __launch_bounds__(256) void k_layer(
    const int* __restrict__ rowptr, const int* __restrict__ csr_src,
    const float* __restrict__ hd_in, const float* __restrict__ Wg,
    const float* __restrict__ bg, const float* __restrict__ dinv,
    const float* __restrict__ xorig, float* __restrict__ hout, int n) {
    constexpr int OPL = (DOUT + DIN - 1) / DIN;
    constexpr int LPG = DIN * (TWOWAY ? 2 : 1);
    __shared__ float sW[DIN * DOUT];
    for (int i = threadIdx.x; i < DIN * DOUT; i += 256) sW[i] = Wg[i];
    __syncthreads();
    const int gpb = 256 / LPG;
    int v = blockIdx.x * gpb + (int)threadIdx.x / LPG;
    int f = threadIdx.x % DIN;
    int way = (threadIdx.x % LPG) / DIN;
    if (v >= n) return;
    int lo = rowptr[v], hi = rowptr[v + 1];
    if (TWOWAY) {  // split edge range between the two ways
        int mid = lo + ((hi - lo) >> 1);
        if (way == 0) hi = mid; else lo = mid;
    }
    float acc = 0.f;
    int j = lo;
    for (; j + 4 <= hi; j += 4) {  // 4 independent gathers in flight
        int s0 = csr_src[j], s1 = csr_src[j + 1], s2 = csr_src[j + 2], s3 = csr_src[j + 3];
        float v0 = hd_in[s0 * DIN + f], v1 = hd_in[s1 * DIN + f];
        float v2 = hd_in[s2 * DIN + f], v3 = hd_in[s3 * DIN + f];
        acc += (v0 + v1) + (v2 + v3);
    }
    for (; j < hi; ++j) acc += hd_in[csr_src[j] * DIN + f];
    if (TWOWAY) {
        acc += __shfl_xor(acc, DIN, 64);  // combine ways
        if (way != 0) return;             // way1 done (width-DIN shfls below stay in-half)
    }
    float dv = dinv[v];
    float aggv = (acc + hd_in[v * DIN + f]) * dv;

    float o[OPL];
#pragma unroll
    for (int k = 0; k < OPL; ++k) {
        int g = f + k * DIN;
        o[k] = (g < DOUT) ? bg[g] : 0.f;
    }
#pragma unroll
    for (int f2 = 0; f2 < DIN; ++f2) {
        float hf = __shfl(aggv, f2, DIN);
#pragma unroll
        for (int k = 0; k < OPL; ++k) {
            int g = f + k * DIN;
            if (g < DOUT) o[k] = fmaf(hf, sW[f2 * DOUT + g], o[k]);
        }
    }
#pragma unroll
    for (int k = 0; k < OPL; ++k) {
        int g = f + k * DIN;
        if (g < DOUT) {
            float r = o[k];
            if (RELU) r = fmaxf(r, 0.f);
            if (LAST) r += xorig[v * 2 + g];
            else r *= dv;
            hout[v * DOUT + g] = r;
        }
    }
}

// ---------------- launch ----------------

extern "C" void kernel_launch(void* const* d_in, const int* in_sizes, int n_in,
                              void* d_out, int out_size, void* d_ws, size_t ws_size,
                              hipStream_t stream) {
    const float* x = (const float*)d_in[0];
    const int* ei = (const int*)d_in[1];  // int32 (harness converts integer inputs)
    const float* W[8];
    const float* B[8];
    for (int i = 0; i < 8; ++i) {
        W[i] = (const float*)d_in[2 + 2 * i];
        B[i] = (const float*)d_in[3 + 2 * i];
    }
    float* out = (float*)d_out;

    char* ws = (char*)d_ws;
    int*   deg     = (int*)  (ws + 0);          //  0.4 MB
    float* dinv    = (float*)(ws + 400128);     //  0.4 MB
    int*   rowptr  = (int*)  (ws + 800256);     //  0.4 MB (n+1)
    int*   cursor  = (int*)  (ws + 1200384);    //  0.4 MB
    int*   exc     = (int*)  (ws + 1600512);    //  0.4 MB
    int*   bsum    = (int*)  (ws + 2000640);    //  tiny
    int*   csr_src = (int*)  (ws + 2001152);    //  6.4 MB
    float* hdA     = (float*)(ws + 8401408);    // 12.8 MB
    float* hdB     = (float*)(ws + 21201408);   // 12.8 MB  (total ~34 MB)

    dim3 blk(256);
    int gN = (NN + 255) / 256;
    int gE = (NE + 255) / 256;

    k_zero_deg<<<gN, blk, 0, stream>>>(deg, NN);
    k_count<<<gE, blk, 0, stream>>>(ei, deg, NE);
    k_scan1<<<NBLK, SCAN_BLK, 0, stream>>>(deg, exc, bsum, NN);
    k_scan2<<<1, 128, 0, stream>>>(bsum, NBLK);
    k_scan3<<<NBLK, SCAN_BLK, 0, stream>>>(exc, bsum, deg, rowptr, cursor, dinv, NN);
    k_fill<<<gE, blk, 0, stream>>>(ei, cursor, csr_src, NE);
    k_prep<<<(2 * NN + 255) / 256, blk, 0, stream>>>(x, dinv, hdA, 2 * NN);

    int g16 = (NN + 15) / 16;    // DIN=16 layers: 16 lanes/group
    int g32 = (NN + 3) / 4;      // DIN=32 two-way: 64 lanes/group, 4 nodes/block

    // L1: hdA(2) -> hdB(16)
    k_layer1<<<g16, blk, 0, stream>>>(rowptr, csr_src, (const float2*)hdA, W[0], B[0], dinv, hdB, NN);
    // L2: hdB(16) -> hdA(32)
    k_layer<16, 32, true, false, false><<<g16, blk, 0, stream>>>(rowptr, csr_src, hdB, W[1], B[1], dinv, x, hdA, NN);
    // L3: hdA(32) -> hdB(32)
    k_layer<32, 32, true, false, true><<<g32, blk, 0, stream>>>(rowptr, csr_src, hdA, W[2], B[2], dinv, x, hdB, NN);
    // L4: hdB -> hdA
    k_layer<32, 32, true, false, true><<<g32, blk, 0, stream>>>(rowptr, csr_src, hdB, W[3], B[3], dinv, x, hdA, NN);
    // L5: hdA -> hdB
    k_layer<32, 32, true, false, true><<<g32, blk, 0, stream>>>(rowptr, csr_src, hdA, W[4], B[4], dinv, x, hdB, NN);
    // L6: hdB -> hdA
    k_layer<32, 32, true, false, true><<<g32, blk, 0, stream>>>(rowptr, csr_src, hdB, W[5], B[5], dinv, x, hdA, NN);
    // L7: hdA(32) -> hdB(16)
    k_layer<32, 16, true, false, true><<<g32, blk, 0, stream>>>(rowptr, csr_src, hdA, W[6], B[6], dinv, x, hdB, NN);
    // L8: hdB(16) -> out(2), +x_orig, no relu
    k_layer<16, 2, false, true, false><<<g16, blk, 0, stream>>>(rowptr, csr_src, hdB, W[7], B[7], dinv, x, out, NN);
}

// Round 6
// 597.738 us; speedup vs baseline: 2.1438x; 1.1214x over previous
//
#include <hip/hip_runtime.h>

#define NN 100000
#define NE 1600000
#define SCAN_BLK 1024
#define NBLK ((NN + SCAN_BLK - 1) / SCAN_BLK)   // 98

#define EB 3072                                  // edges per bucket-block
#define NBE ((NE + EB - 1) / EB)                 // 521
#define NBUCK ((NN + 511) >> 9)                  // 196 buckets of 512 dst nodes
#define BCAP 9216                                // pairs capacity per bucket (exp 8192, sd 90)

// ---------------- structure precompute ----------------

__global__ void k_zero(int* __restrict__ deg, int* __restrict__ bcur, int n) {
    int i = blockIdx.x * blockDim.x + threadIdx.x;
    if (i < n) deg[i] = 0;
    if (i < NBUCK) bcur[i] = i * BCAP;
}

// chunk edges -> per-bucket contiguous runs of (dst,src) pairs; fused degree count
__global__ __launch_bounds__(256) void k_bucket(
    const int* __restrict__ ei, int* __restrict__ deg,
    int* __restrict__ bcur, long long* __restrict__ pairs, int nE) {
    __shared__ int cnt[NBUCK];
    __shared__ int sc[NBUCK];
    __shared__ int rc[NBUCK];
    __shared__ int gbase[NBUCK];
    __shared__ int tmp[256];
    __shared__ long long st[EB];

    int base = blockIdx.x * EB;
    int lim = nE - base; if (lim > EB) lim = EB;
    int tid = threadIdx.x;

    for (int i = tid; i < NBUCK; i += 256) cnt[i] = 0;
    __syncthreads();
    // pass A: bucket counts + global degree
    for (int i = tid; i < lim; i += 256) {
        int d = ei[nE + base + i];
        atomicAdd(&cnt[d >> 9], 1);
        atomicAdd(&deg[d], 1);
    }
    __syncthreads();
    // block scan of bucket counts (inclusive -> exclusive)
    {
        int v = (tid < NBUCK) ? cnt[tid] : 0;
        tmp[tid] = v;
        __syncthreads();
        for (int off = 1; off < 256; off <<= 1) {
            int add = (tid >= off) ? tmp[tid - off] : 0;
            __syncthreads();
            tmp[tid] += add;
            __syncthreads();
        }
        if (tid < NBUCK) {
            int e = tmp[tid] - v;
            sc[tid] = e;
            rc[tid] = e;
            gbase[tid] = (v > 0) ? atomicAdd(&bcur[tid], v) : 0;
        }
    }
    __syncthreads();
    // pass B: place pairs into LDS grouped by bucket
    for (int i = tid; i < lim; i += 256) {
        int s = ei[base + i];
        int d = ei[nE + base + i];
        int p = atomicAdd(&rc[d >> 9], 1);
        st[p] = ((long long)d << 32) | (unsigned int)s;
    }
    __syncthreads();
    // pass C: stream out per-bucket runs (coalesced within runs)
    for (int i = tid; i < lim; i += 256) {
        long long pr = st[i];
        int d = (int)(pr >> 32);
        int b = d >> 9;
        pairs[gbase[b] + (i - sc[b])] = pr;
    }
}

__global__ __launch_bounds__(SCAN_BLK) void k_scan1(
    const int* __restrict__ deg, int* __restrict__ exc, int* __restrict__ bsum, int n) {
    __shared__ int sh[SCAN_BLK];
    int tid = threadIdx.x;
    int i = blockIdx.x * SCAN_BLK + tid;
    int v = (i < n) ? deg[i] : 0;
    sh[tid] = v;
    __syncthreads();
    for (int off = 1; off < SCAN_BLK; off <<= 1) {
        int add = (tid >= off) ? sh[tid - off] : 0;
        __syncthreads();
        sh[tid] += add;
        __syncthreads();
    }
    if (i < n) exc[i] = sh[tid] - v;
    if (tid == SCAN_BLK - 1) bsum[blockIdx.x] = sh[tid];
}

__global__ __launch_bounds__(128) void k_scan2(int* __restrict__ bsum, int nb) {
    __shared__ int sh[128];
    int tid = threadIdx.x;
    int v = (tid < nb) ? bsum[tid] : 0;
    sh[tid] = v;
    __syncthreads();
    for (int off = 1; off < 128; off <<= 1) {
        int add = (tid >= off) ? sh[tid - off] : 0;
        __syncthreads();
        sh[tid] += add;
        __syncthreads();
    }
    if (tid < nb) bsum[tid] = sh[tid] - v;  // exclusive
}

// rowptr/cursor + dinv + fused hd0 = x*dinv
__global__ __launch_bounds__(SCAN_BLK) void k_scan3(
    const int* __restrict__ exc, const int* __restrict__ bsum,
    const int* __restrict__ deg, const float* __restrict__ x,
    int* __restrict__ rowptr, int* __restrict__ cursor,
    float* __restrict__ dinv, float* __restrict__ hd0, int n) {
    int i = blockIdx.x * SCAN_BLK + threadIdx.x;
    if (i >= n) return;
    int r = exc[i] + bsum[blockIdx.x];
    rowptr[i] = r;
    cursor[i] = r;
    float dv = rsqrtf((float)(deg[i] + 1));  // +1 = self loop
    dinv[i] = dv;
    hd0[2 * i]     = x[2 * i] * dv;
    hd0[2 * i + 1] = x[2 * i + 1] * dv;
    if (i == 0) rowptr[n] = NE;
}

// one block per bucket: scatter confined to the bucket's csr range (L2-resident)
__global__ __launch_bounds__(256) void k_fill2(
    const long long* __restrict__ pairs, const int* __restrict__ bcur,
    int* __restrict__ cursor, int* __restrict__ csr_src) {
    int b = blockIdx.x;
    int gb = b * BCAP;
    int cnt = bcur[b] - gb;
    for (int i = threadIdx.x; i < cnt; i += 256) {
        long long pr = pairs[gb + i];
        int d = (int)(pr >> 32);
        int s = (int)(pr & 0xffffffffLL);
        int pos = atomicAdd(&cursor[d], 1);
        csr_src[pos] = s;
    }
}

// ---------------- layer kernels ----------------
// Layer math: agg[v] = dinv[v] * (sum_{j in row(v)} hd_in[src_j] + hd_in[v])
//             o      = agg @ W + b ;  hd_out = relu(o)*dinv  (or o + xorig if LAST)

// L1 special: DIN=2. Group of 16 lanes splits the edge list; butterfly reduce.
__global__ __launch_bounds__(256) void k_layer1(
    const int* __restrict__ rowptr, const int* __restrict__ csr_src,
    const float2* __restrict__ hd0, const float* __restrict__ Wg,
    const float* __restrict__ bg, const float* __restrict__ dinv,
    float* __restrict__ hd1, int n) {
    __shared__ float sW[32];
    if (threadIdx.x < 32) sW[threadIdx.x] = Wg[threadIdx.x];
    __syncthreads();
    int v = blockIdx.x * 16 + threadIdx.x / 16;
    int l = threadIdx.x & 15;
    if (v >= n) return;
    int lo = rowptr[v], hi = rowptr[v + 1];
    float a0 = 0.f, a1 = 0.f;
    for (int j = lo + l; j < hi; j += 16) {
        float2 h = hd0[csr_src[j]];
        a0 += h.x; a1 += h.y;
    }
#pragma unroll
    for (int off = 8; off >= 1; off >>= 1) {
        a0 += __shfl_xor(a0, off, 16);
        a1 += __shfl_xor(a1, off, 16);
    }
    float dv = dinv[v];
    float2 hs = hd0[v];
    a0 = (a0 + hs.x) * dv;
    a1 = (a1 + hs.y) * dv;
    float o = bg[l] + a0 * sW[l] + a1 * sW[16 + l];   // W is (2,16) row-major
    hd1[v * 16 + l] = fmaxf(o, 0.f) * dv;
}

// Generic layer. Lanes-per-group = DIN * (TWOWAY?2:1); feature lane f, edge-way.
template <int DIN, int DOUT, bool RELU, bool LAST, bool TWOWAY>
__global__ __launch_bounds__(256) void k_layer(
    const int* __restrict__ rowptr, const int* __restrict__ csr_src,
    const float* __restrict__ hd_in, const float* __restrict__ Wg,
    const float* __restrict__ bg, const float* __restrict__ dinv,
    const float* __restrict__ xorig, float* __restrict__ hout, int n) {
    constexpr int OPL = (DOUT + DIN - 1) / DIN;
    constexpr int LPG = DIN * (TWOWAY ? 2 : 1);
    __shared__ float sW[DIN * DOUT];
    for (int i = threadIdx.x; i < DIN * DOUT; i += 256) sW[i] = Wg[i];
    __syncthreads();
    const int gpb = 256 / LPG;
    int v = blockIdx.x * gpb + (int)threadIdx.x / LPG;
    int f = threadIdx.x % DIN;
    int way = (threadIdx.x % LPG) / DIN;
    if (v >= n) return;
    int lo = rowptr[v], hi = rowptr[v + 1];
    if (TWOWAY) {  // split edge range between the two ways
        int mid = lo + ((hi - lo) >> 1);
        if (way == 0) hi = mid; else lo = mid;
    }
    float acc = 0.f;
    int j = lo;
    for (; j + 4 <= hi; j += 4) {  // 4 independent gathers in flight
        int s0 = csr_src[j], s1 = csr_src[j + 1], s2 = csr_src[j + 2], s3 = csr_src[j + 3];
        float v0 = hd_in[s0 * DIN + f], v1 = hd_in[s1 * DIN + f];
        float v2 = hd_in[s2 * DIN + f], v3 = hd_in[s3 * DIN + f];
        acc += (v0 + v1) + (v2 + v3);
    }
    for (; j < hi; ++j) acc += hd_in[csr_src[j] * DIN + f];
    if (TWOWAY) {
        acc += __shfl_xor(acc, DIN, 64);  // combine ways
        if (way != 0) return;             // width-DIN shfls below stay in-half
    }
    float dv = dinv[v];
    float aggv = (acc + hd_in[v * DIN + f]) * dv;

    float o[OPL];
#pragma unroll
    for (int k = 0; k < OPL; ++k) {
        int g = f + k * DIN;
        o[k] = (g < DOUT) ? bg[g] : 0.f;
    }
#pragma unroll
    for (int f2 = 0; f2 < DIN; ++f2) {
        float hf = __shfl(aggv, f2, DIN);
#pragma unroll
        for (int k = 0; k < OPL; ++k) {
            int g = f + k * DIN;
            if (g < DOUT) o[k] = fmaf(hf, sW[f2 * DOUT + g], o[k]);
        }
    }
#pragma unroll
    for (int k = 0; k < OPL; ++k) {
        int g = f + k * DIN;
        if (g < DOUT) {
            float r = o[k];
            if (RELU) r = fmaxf(r, 0.f);
            if (LAST) r += xorig[v * 2 + g];
            else r *= dv;
            hout[v * DOUT + g] = r;
        }
    }
}

// ---------------- launch ----------------

extern "C" void kernel_launch(void* const* d_in, const int* in_sizes, int n_in,
                              void* d_out, int out_size, void* d_ws, size_t ws_size,
                              hipStream_t stream) {
    const float* x = (const float*)d_in[0];
    const int* ei = (const int*)d_in[1];  // int32 (harness converts integer inputs)
    const float* W[8];
    const float* B[8];
    for (int i = 0; i < 8; ++i) {
        W[i] = (const float*)d_in[2 + 2 * i];
        B[i] = (const float*)d_in[3 + 2 * i];
    }
    float* out = (float*)d_out;

    char* ws = (char*)d_ws;
    int*       deg     = (int*)      (ws + 0);          //  0.4 MB
    float*     dinv    = (float*)    (ws + 400128);     //  0.4 MB
    int*       rowptr  = (int*)      (ws + 800256);     //  0.4 MB (n+1)
    int*       cursor  = (int*)      (ws + 1200384);    //  0.4 MB
    int*       exc     = (int*)      (ws + 1600512);    //  0.4 MB
    int*       bsum    = (int*)      (ws + 2000640);    //  tiny
    int*       bcur    = (int*)      (ws + 2001152);    //  tiny
    long long* pairs   = (long long*)(ws + 2002176);    // 14.45 MB
    int*       csr_src = (int*)      (ws + 16452864);   //  6.4 MB
    float*     hdA     = (float*)    (ws + 22852992);   // 12.8 MB
    float*     hdB     = (float*)    (ws + 35653120);   // 12.8 MB  (total ~48.5 MB)

    dim3 blk(256);
    int gN = (NN + 255) / 256;

    k_zero<<<gN, blk, 0, stream>>>(deg, bcur, NN);
    k_bucket<<<NBE, blk, 0, stream>>>(ei, deg, bcur, pairs, NE);
    k_scan1<<<NBLK, SCAN_BLK, 0, stream>>>(deg, exc, bsum, NN);
    k_scan2<<<1, 128, 0, stream>>>(bsum, NBLK);
    k_scan3<<<NBLK, SCAN_BLK, 0, stream>>>(exc, bsum, deg, x, rowptr, cursor, dinv, hdA, NN);
    k_fill2<<<NBUCK, blk, 0, stream>>>(pairs, bcur, cursor, csr_src);

    int g16 = (NN + 15) / 16;    // DIN=16 layers: 16 lanes/group
    int g32 = (NN + 3) / 4;      // DIN=32 two-way: 64 lanes/group, 4 nodes/block

    // L1: hdA(2) -> hdB(16)
    k_layer1<<<g16, blk, 0, stream>>>(rowptr, csr_src, (const float2*)hdA, W[0], B[0], dinv, hdB, NN);
    // L2: hdB(16) -> hdA(32)
    k_layer<16, 32, true, false, false><<<g16, blk, 0, stream>>>(rowptr, csr_src, hdB, W[1], B[1], dinv, x, hdA, NN);
    // L3: hdA(32) -> hdB(32)
    k_layer<32, 32, true, false, true><<<g32, blk, 0, stream>>>(rowptr, csr_src, hdA, W[2], B[2], dinv, x, hdB, NN);
    // L4: hdB -> hdA
    k_layer<32, 32, true, false, true><<<g32, blk, 0, stream>>>(rowptr, csr_src, hdB, W[3], B[3], dinv, x, hdA, NN);
    // L5: hdA -> hdB
    k_layer<32, 32, true, false, true><<<g32, blk, 0, stream>>>(rowptr, csr_src, hdA, W[4], B[4], dinv, x, hdB, NN);
    // L6: hdB -> hdA
    k_layer<32, 32, true, false, true><<<g32, blk, 0, stream>>>(rowptr, csr_src, hdB, W[5], B[5], dinv, x, hdA, NN);
    // L7: hdA(32) -> hdB(16)
    k_layer<32, 16, true, false, true><<<g32, blk, 0, stream>>>(rowptr, csr_src, hdA, W[6], B[6], dinv, x, hdB, NN);
    // L8: hdB(16) -> out(2), +x_orig, no relu
    k_layer<16, 2, false, true, false><<<g16, blk, 0, stream>>>(rowptr, csr_src, hdB, W[7], B[7], dinv, x, out, NN);
}

// Round 7
// 519.018 us; speedup vs baseline: 2.4689x; 1.1517x over previous
//
#include <hip/hip_runtime.h>
#include <hip/hip_fp16.h>

#define NN 100000
#define NE 1600000
#define SCAN_BLK 1024
#define NBLK ((NN + SCAN_BLK - 1) / SCAN_BLK)   // 98

#define EB 3072                                  // edges per bucket-block chunk
#define NBE ((NE + EB - 1) / EB)                 // 521
#define BSH 10                                   // 1024-node buckets
#define NBUCK ((NN + 1023) >> BSH)               // 98
#define BCAP 18432                               // pairs cap/bucket (exp 16327, sd ~127)

// ---------------- structure precompute ----------------

__global__ void k_init(int* __restrict__ bcur) {
    int i = blockIdx.x * blockDim.x + threadIdx.x;
    if (i < NBUCK) bcur[i] = i * BCAP;
}

// chunk edges -> per-bucket contiguous runs of (dst,src) pairs (no global atomics on deg)
__global__ __launch_bounds__(256) void k_bucket(
    const int* __restrict__ ei, int* __restrict__ bcur,
    long long* __restrict__ pairs, int nE) {
    __shared__ int cnt[NBUCK];
    __shared__ int sc[NBUCK];
    __shared__ int rc[NBUCK];
    __shared__ int gbase[NBUCK];
    __shared__ int tmp[256];
    __shared__ long long st[EB];

    int base = blockIdx.x * EB;
    int lim = nE - base; if (lim > EB) lim = EB;
    int tid = threadIdx.x;

    for (int i = tid; i < NBUCK; i += 256) cnt[i] = 0;
    __syncthreads();
    // pass A: bucket counts
    for (int i = tid; i < lim; i += 256) {
        int d = ei[nE + base + i];
        atomicAdd(&cnt[d >> BSH], 1);
    }
    __syncthreads();
    // block scan of bucket counts -> exclusive offsets + global reservation
    {
        int v = (tid < NBUCK) ? cnt[tid] : 0;
        tmp[tid] = v;
        __syncthreads();
        for (int off = 1; off < 256; off <<= 1) {
            int add = (tid >= off) ? tmp[tid - off] : 0;
            __syncthreads();
            tmp[tid] += add;
            __syncthreads();
        }
        if (tid < NBUCK) {
            int e = tmp[tid] - v;
            sc[tid] = e;
            rc[tid] = e;
            gbase[tid] = (v > 0) ? atomicAdd(&bcur[tid], v) : 0;
        }
    }
    __syncthreads();
    // pass B: group pairs by bucket in LDS
    for (int i = tid; i < lim; i += 256) {
        int s = ei[base + i];
        int d = ei[nE + base + i];
        int p = atomicAdd(&rc[d >> BSH], 1);
        st[p] = ((long long)d << 32) | (unsigned int)s;
    }
    __syncthreads();
    // pass C: stream out per-bucket runs (long coalesced runs)
    for (int i = tid; i < lim; i += 256) {
        long long pr = st[i];
        int b = (int)(pr >> 32) >> BSH;
        pairs[gbase[b] + (i - sc[b])] = pr;
    }
}

// per-bucket LDS histogram -> coalesced non-atomic deg write
__global__ __launch_bounds__(256) void k_count2(
    const long long* __restrict__ pairs, const int* __restrict__ bcur,
    int* __restrict__ deg) {
    __shared__ int cnt[1 << BSH];
    int b = blockIdx.x;
    int gb = b * BCAP;
    int m = bcur[b] - gb;
    for (int i = threadIdx.x; i < (1 << BSH); i += 256) cnt[i] = 0;
    __syncthreads();
    for (int i = threadIdx.x; i < m; i += 256) {
        int d = (int)(pairs[gb + i] >> 32);
        atomicAdd(&cnt[d & ((1 << BSH) - 1)], 1);
    }
    __syncthreads();
    int base = b << BSH;
    for (int i = threadIdx.x; i < (1 << BSH); i += 256) {
        int v = base + i;
        if (v < NN) deg[v] = cnt[i];
    }
}

__global__ __launch_bounds__(SCAN_BLK) void k_scan1(
    const int* __restrict__ deg, int* __restrict__ exc, int* __restrict__ bsum, int n) {
    __shared__ int sh[SCAN_BLK];
    int tid = threadIdx.x;
    int i = blockIdx.x * SCAN_BLK + tid;
    int v = (i < n) ? deg[i] : 0;
    sh[tid] = v;
    __syncthreads();
    for (int off = 1; off < SCAN_BLK; off <<= 1) {
        int add = (tid >= off) ? sh[tid - off] : 0;
        __syncthreads();
        sh[tid] += add;
        __syncthreads();
    }
    if (i < n) exc[i] = sh[tid] - v;
    if (tid == SCAN_BLK - 1) bsum[blockIdx.x] = sh[tid];
}

__global__ __launch_bounds__(128) void k_scan2(int* __restrict__ bsum, int nb) {
    __shared__ int sh[128];
    int tid = threadIdx.x;
    int v = (tid < nb) ? bsum[tid] : 0;
    sh[tid] = v;
    __syncthreads();
    for (int off = 1; off < 128; off <<= 1) {
        int add = (tid >= off) ? sh[tid - off] : 0;
        __syncthreads();
        sh[tid] += add;
        __syncthreads();
    }
    if (tid < nb) bsum[tid] = sh[tid] - v;  // exclusive
}

// rowptr + dinv + hd0 = x*dinv (fp16)
__global__ __launch_bounds__(SCAN_BLK) void k_scan3(
    const int* __restrict__ exc, const int* __restrict__ bsum,
    const int* __restrict__ deg, const float* __restrict__ x,
    int* __restrict__ rowptr, float* __restrict__ dinv,
    __half2* __restrict__ hd0, int n) {
    int i = blockIdx.x * SCAN_BLK + threadIdx.x;
    if (i >= n) return;
    rowptr[i] = exc[i] + bsum[blockIdx.x];
    float dv = rsqrtf((float)(deg[i] + 1));  // +1 = self loop
    dinv[i] = dv;
    hd0[i] = __floats2half2_rn(x[2 * i] * dv, x[2 * i + 1] * dv);
    if (i == 0) rowptr[n] = NE;
}

// per-bucket scatter: LDS cursors (seeded from rowptr), csr writes confined to bucket window
__global__ __launch_bounds__(256) void k_fill3(
    const long long* __restrict__ pairs, const int* __restrict__ bcur,
    const int* __restrict__ rowptr, int* __restrict__ csr_src) {
    __shared__ int lcur[1 << BSH];
    int b = blockIdx.x;
    int gb = b * BCAP;
    int m = bcur[b] - gb;
    int base = b << BSH;
    for (int i = threadIdx.x; i < (1 << BSH); i += 256) {
        int v = base + i;
        lcur[i] = (v < NN) ? rowptr[v] : 0;
    }
    __syncthreads();
    for (int i = threadIdx.x; i < m; i += 256) {
        long long pr = pairs[gb + i];
        int d = (int)(pr >> 32);
        int s = (int)(pr & 0xffffffffLL);
        int pos = atomicAdd(&lcur[d & ((1 << BSH) - 1)], 1);
        csr_src[pos] = s;
    }
}

// ---------------- layer kernels ----------------
// agg[v] = dinv[v] * (sum_j hd_in[src_j] + hd_in[v]) ; o = agg@W + b
// hd_out = relu(o)*dinv (fp16)   |  LAST: out = o + xorig (fp32)

// L1: DIN=2, half2 rows; 16-lane edge-split + butterfly.
__global__ __launch_bounds__(256) void k_layer1(
    const int* __restrict__ rowptr, const int* __restrict__ csr_src,
    const __half2* __restrict__ hd0, const float* __restrict__ Wg,
    const float* __restrict__ bg, const float* __restrict__ dinv,
    __half* __restrict__ hd1, int n) {
    __shared__ float sW[32];
    if (threadIdx.x < 32) sW[threadIdx.x] = Wg[threadIdx.x];
    __syncthreads();
    int v = blockIdx.x * 16 + threadIdx.x / 16;
    int l = threadIdx.x & 15;
    if (v >= n) return;
    int lo = rowptr[v], hi = rowptr[v + 1];
    float a0 = 0.f, a1 = 0.f;
    for (int j = lo + l; j < hi; j += 16) {
        float2 h = __half22float2(hd0[csr_src[j]]);
        a0 += h.x; a1 += h.y;
    }
#pragma unroll
    for (int off = 8; off >= 1; off >>= 1) {
        a0 += __shfl_xor(a0, off, 16);
        a1 += __shfl_xor(a1, off, 16);
    }
    float dv = dinv[v];
    float2 hs = __half22float2(hd0[v]);
    a0 = (a0 + hs.x) * dv;
    a1 = (a1 + hs.y) * dv;
    float o = bg[l] + a0 * sW[l] + a1 * sW[16 + l];   // W is (2,16) row-major
    hd1[v * 16 + l] = __float2half(fmaxf(o, 0.f) * dv);
}

// Generic layer, fp16 hd. Lanes/group = DIN*(TWOWAY?2:1).
template <int DIN, int DOUT, bool RELU, bool LAST, bool TWOWAY>
__global__ __launch_bounds__(256) void k_layer(
    const int* __restrict__ rowptr, const int* __restrict__ csr_src,
    const __half* __restrict__ hd_in, const float* __restrict__ Wg,
    const float* __restrict__ bg, const float* __restrict__ dinv,
    const float* __restrict__ xorig, __half* __restrict__ hout_h,
    float* __restrict__ hout_f, int n) {
    constexpr int OPL = (DOUT + DIN - 1) / DIN;
    constexpr int LPG = DIN * (TWOWAY ? 2 : 1);
    __shared__ float sW[DIN * DOUT];
    for (int i = threadIdx.x; i < DIN * DOUT; i += 256) sW[i] = Wg[i];
    __syncthreads();
    const int gpb = 256 / LPG;
    int v = blockIdx.x * gpb + (int)threadIdx.x / LPG;
    int f = threadIdx.x % DIN;
    int way = (threadIdx.x % LPG) / DIN;
    if (v >= n) return;
    int lo = rowptr[v], hi = rowptr[v + 1];
    if (TWOWAY) {
        int mid = lo + ((hi - lo) >> 1);
        if (way == 0) hi = mid; else lo = mid;
    }
    float acc = 0.f;
    int j = lo;
    for (; j + 4 <= hi; j += 4) {  // 4 independent gathers in flight
        int s0 = csr_src[j], s1 = csr_src[j + 1], s2 = csr_src[j + 2], s3 = csr_src[j + 3];
        float v0 = __half2float(hd_in[s0 * DIN + f]);
        float v1 = __half2float(hd_in[s1 * DIN + f]);
        float v2 = __half2float(hd_in[s2 * DIN + f]);
        float v3 = __half2float(hd_in[s3 * DIN + f]);
        acc += (v0 + v1) + (v2 + v3);
    }
    for (; j < hi; ++j) acc += __half2float(hd_in[csr_src[j] * DIN + f]);
    if (TWOWAY) {
        acc += __shfl_xor(acc, DIN, 64);  // combine ways
        if (way != 0) return;             // width-DIN shfls below stay in-half
    }
    float dv = dinv[v];
    float aggv = (acc + __half2float(hd_in[v * DIN + f])) * dv;

    float o[OPL];
#pragma unroll
    for (int k = 0; k < OPL; ++k) {
        int g = f + k * DIN;
        o[k] = (g < DOUT) ? bg[g] : 0.f;
    }
#pragma unroll
    for (int f2 = 0; f2 < DIN; ++f2) {
        float hf = __shfl(aggv, f2, DIN);
#pragma unroll
        for (int k = 0; k < OPL; ++k) {
            int g = f + k * DIN;
            if (g < DOUT) o[k] = fmaf(hf, sW[f2 * DOUT + g], o[k]);
        }
    }
#pragma unroll
    for (int k = 0; k < OPL; ++k) {
        int g = f + k * DIN;
        if (g < DOUT) {
            float r = o[k];
            if (RELU) r = fmaxf(r, 0.f);
            if (LAST) hout_f[v * DOUT + g] = r + xorig[v * 2 + g];
            else      hout_h[v * DOUT + g] = __float2half(r * dv);
        }
    }
}

// ---------------- launch ----------------

extern "C" void kernel_launch(void* const* d_in, const int* in_sizes, int n_in,
                              void* d_out, int out_size, void* d_ws, size_t ws_size,
                              hipStream_t stream) {
    const float* x = (const float*)d_in[0];
    const int* ei = (const int*)d_in[1];  // int32 (harness converts integer inputs)
    const float* W[8];
    const float* B[8];
    for (int i = 0; i < 8; ++i) {
        W[i] = (const float*)d_in[2 + 2 * i];
        B[i] = (const float*)d_in[3 + 2 * i];
    }
    float* out = (float*)d_out;

    char* ws = (char*)d_ws;
    int*       deg     = (int*)      (ws + 0);          //  0.4 MB
    float*     dinv    = (float*)    (ws + 400128);     //  0.4 MB
    int*       rowptr  = (int*)      (ws + 800256);     //  0.4 MB (n+1)
    int*       exc     = (int*)      (ws + 1200384);    //  0.4 MB
    int*       bsum    = (int*)      (ws + 1600512);    //  tiny
    int*       bcur    = (int*)      (ws + 1601024);    //  tiny
    long long* pairs   = (long long*)(ws + 1601536);    // 14.45 MB
    int*       csr_src = (int*)      (ws + 16052224);   //  6.4 MB
    __half*    hdA     = (__half*)   (ws + 22452224);   //  6.4 MB
    __half*    hdB     = (__half*)   (ws + 28852224);   //  6.4 MB  (total ~35.3 MB)

    dim3 blk(256);

    k_init<<<1, 128, 0, stream>>>(bcur);
    k_bucket<<<NBE, blk, 0, stream>>>(ei, bcur, pairs, NE);
    k_count2<<<NBUCK, blk, 0, stream>>>(pairs, bcur, deg);
    k_scan1<<<NBLK, SCAN_BLK, 0, stream>>>(deg, exc, bsum, NN);
    k_scan2<<<1, 128, 0, stream>>>(bsum, NBLK);
    k_scan3<<<NBLK, SCAN_BLK, 0, stream>>>(exc, bsum, deg, x, rowptr, dinv, (__half2*)hdA, NN);
    k_fill3<<<NBUCK, blk, 0, stream>>>(pairs, bcur, rowptr, csr_src);

    int g16 = (NN + 15) / 16;    // DIN=16 layers: 16 lanes/group
    int g32 = (NN + 3) / 4;      // DIN=32 two-way: 64 lanes/group, 4 nodes/block

    // L1: hdA(2) -> hdB(16)
    k_layer1<<<g16, blk, 0, stream>>>(rowptr, csr_src, (const __half2*)hdA, W[0], B[0], dinv, hdB, NN);
    // L2: hdB(16) -> hdA(32)
    k_layer<16, 32, true, false, false><<<g16, blk, 0, stream>>>(rowptr, csr_src, hdB, W[1], B[1], dinv, x, hdA, out, NN);
    // L3: hdA(32) -> hdB(32)
    k_layer<32, 32, true, false, true><<<g32, blk, 0, stream>>>(rowptr, csr_src, hdA, W[2], B[2], dinv, x, hdB, out, NN);
    // L4: hdB -> hdA
    k_layer<32, 32, true, false, true><<<g32, blk, 0, stream>>>(rowptr, csr_src, hdB, W[3], B[3], dinv, x, hdA, out, NN);
    // L5: hdA -> hdB
    k_layer<32, 32, true, false, true><<<g32, blk, 0, stream>>>(rowptr, csr_src, hdA, W[4], B[4], dinv, x, hdB, out, NN);
    // L6: hdB -> hdA
    k_layer<32, 32, true, false, true><<<g32, blk, 0, stream>>>(rowptr, csr_src, hdB, W[5], B[5], dinv, x, hdA, out, NN);
    // L7: hdA(32) -> hdB(16)
    k_layer<32, 16, true, false, true><<<g32, blk, 0, stream>>>(rowptr, csr_src, hdA, W[6], B[6], dinv, x, hdB, out, NN);
    // L8: hdB(16) -> out(2), +x_orig, no relu
    k_layer<16, 2, false, true, false><<<g16, blk, 0, stream>>>(rowptr, csr_src, hdB, W[7], B[7], dinv, x, hdA, out, NN);
}